// Round 7
// baseline (102.655 us; speedup 1.0000x reference)
//
#include <hip/hip_runtime.h>
#include <hip/hip_bf16.h>

#define M_TOK 2048
#define KDIM  4096
#define NDIM  4096
#define BM    256
#define BN    64
#define BK    64
#define NT    (KDIM / BK)          // 64 K-tiles
#define AREG  (BM * BK)            // 16384 ushorts (32 KB)
#define BREG  (BN * BK)            // 4096 ushorts (8 KB)
#define BUFSZ (AREG + BREG)        // 20480 ushorts (40 KB)

typedef __bf16 bf16x8 __attribute__((ext_vector_type(8)));
typedef float  f32x4  __attribute__((ext_vector_type(4)));
typedef short  short8 __attribute__((ext_vector_type(8)));

__device__ __forceinline__ ushort f2bf(float f) {
    union { float f; unsigned u; } v; v.f = f;
    unsigned r = (v.u + 0x7fffu + ((v.u >> 16) & 1u)) >> 16;
    return (ushort)r;
}

__device__ __forceinline__ void gload16(const ushort* g, ushort* l) {
    __builtin_amdgcn_global_load_lds(
        (const __attribute__((address_space(1))) void*)g,
        (__attribute__((address_space(3))) void*)l, 16, 0, 0);
}

// ---------------- kernel 1: cast x -> bf16  AND  build W3 (merged) ----------------
// blocks 0..4095: cast 8 floats/thread. blocks 4096..8191: one W3 row each.
__global__ __launch_bounds__(256) void k_prep(const float* __restrict__ x,
                                              ushort* __restrict__ xb,
                                              const float* __restrict__ g0,
                                              const float* __restrict__ g1,
                                              const float* __restrict__ alpha,
                                              const float* __restrict__ pds,
                                              const int* __restrict__ iperm,
                                              const int* __restrict__ oinv,
                                              ushort* __restrict__ W3) {
    __shared__ float  G0s[1024];   // [j0][r]
    __shared__ float  G1s[1024];   // [r][j1]
    __shared__ ushort rowb[4096];
    const int b = blockIdx.x;
    if (b < 4096) {
        const int i = (b * 256 + threadIdx.x) * 8;
        float4 a = *reinterpret_cast<const float4*>(x + i);
        float4 c = *reinterpret_cast<const float4*>(x + i + 4);
        short8 o;
        o[0] = (short)f2bf(a.x); o[1] = (short)f2bf(a.y);
        o[2] = (short)f2bf(a.z); o[3] = (short)f2bf(a.w);
        o[4] = (short)f2bf(c.x); o[5] = (short)f2bf(c.y);
        o[6] = (short)f2bf(c.z); o[7] = (short)f2bf(c.w);
        *reinterpret_cast<short8*>(xb + i) = o;
        return;
    }
    const int o  = b - 4096;
    const int op = oinv[o];
    const int i0 = op >> 6, i1 = op & 63;
    const float sc = alpha[0] * pds[op];

    for (int idx = threadIdx.x; idx < 1024; idx += 256) {
        G0s[idx] = g0[i0 * 1024 + idx];
        G1s[idx] = g1[(idx >> 6) * 4096 + i1 * 64 + (idx & 63)];
    }
    __syncthreads();
    for (int jp = threadIdx.x; jp < 4096; jp += 256) {
        const int j0 = jp >> 6, j1 = jp & 63;
        float v = 0.f;
#pragma unroll
        for (int r = 0; r < 16; ++r)
            v = fmaf(G0s[j0 * 16 + r], G1s[r * 64 + j1], v);
        rowb[iperm[jp]] = f2bf(v * sc);
    }
    __syncthreads();
    for (int t = threadIdx.x; t < 512; t += 256)
        *reinterpret_cast<short8*>(W3 + (size_t)o * 4096 + t * 8) =
            *reinterpret_cast<const short8*>(rowb + t * 8);
}

// ---------------- kernel 2: C = A @ B^T + bias ----------------
// BM=256 x BN=64, BK=64, 256 thr = 4 waves stacked in M (wave tile 64x64),
// 16x16x32 MFMA, dbuf LDS 80KB -> 2 blocks/CU, counted vmcnt(10),
// R5-verified zero-conflict swizzle (byte ^= (row&7)<<4, 128B rows).
__global__ __launch_bounds__(256, 2)
void k_gemm(const ushort* __restrict__ A, const ushort* __restrict__ B,
            const float* __restrict__ bias, float* __restrict__ C) {
    __shared__ __align__(16) ushort lds[2 * BUFSZ];   // 80 KB
    const int tid  = threadIdx.x;
    const int lane = tid & 63;
    const int w    = tid >> 6;   // 0..3, wave owns rows w*64..w*64+63

    // XCD map: grid 512 = 8(by) x 64(bx); each XCD owns a 4x16 rectangle
    const int bid = blockIdx.x;
    const int xcd = bid & 7, li = bid >> 3;       // li 0..63
    const int by = (xcd >> 2) * 4 + (li >> 4);    // 0..7
    const int bx = (xcd & 3) * 16 + (li & 15);    // 0..63
    const long brow = (long)by * BM, bcol = (long)bx * BN;

    // ---- staging: 10 gload16/thread/tile (A 8 units, B 2 units of 32 rows).
    // thread t -> unit-row t>>3, LDS slot t&7; global slot pre-swizzled ^ (row&7)
    const int rhat = tid >> 3;
    const int scol = ((tid & 7) ^ (rhat & 7)) << 3;
    const ushort* gA0 = A + (size_t)(brow + rhat) * KDIM + scol;
    const ushort* gB0 = B + (size_t)(bcol + rhat) * KDIM + scol;
    const int wub = (tid & ~63) * 8;   // wave-uniform LDS base (w*512)

    auto stage = [&](int bufo, int kt) {
#pragma unroll
        for (int q = 0; q < 8; ++q)
            gload16(gA0 + (size_t)(q * 32) * KDIM + kt,
                    (ushort*)lds + bufo + q * 2048 + wub);
#pragma unroll
        for (int q = 0; q < 2; ++q)
            gload16(gB0 + (size_t)(q * 32) * KDIM + kt,
                    (ushort*)lds + bufo + AREG + q * 2048 + wub);
    };

    // ---- fragment-read geometry (R5-verified swizzle, 128B rows)
    const int lr = lane & 15;
    int colswz[2];
#pragma unroll
    for (int kk = 0; kk < 2; ++kk)
        colswz[kk] = (((kk << 6) | ((lane >> 4) << 4)) ^ ((lane & 7) << 4)) >> 1;
    const int rowA = (w * 64 + lr) * 64;   // + m*1024
    const int rowB = lr * 64;              // + n*1024 (B region)

    f32x4 acc[4][4] = {};

    auto compute = [&](int bufo) {
#pragma unroll
        for (int kk = 0; kk < 2; ++kk) {
            bf16x8 af[4], bfr[4];
#pragma unroll
            for (int m = 0; m < 4; ++m)
                af[m] = *reinterpret_cast<const bf16x8*>(
                    lds + bufo + rowA + m * 1024 + colswz[kk]);
#pragma unroll
            for (int n = 0; n < 4; ++n)
                bfr[n] = *reinterpret_cast<const bf16x8*>(
                    lds + bufo + AREG + rowB + n * 1024 + colswz[kk]);
            __builtin_amdgcn_s_setprio(1);
#pragma unroll
            for (int m = 0; m < 4; ++m)
#pragma unroll
                for (int n = 0; n < 4; ++n)
                    acc[m][n] = __builtin_amdgcn_mfma_f32_16x16x32_bf16(
                        af[m], bfr[n], acc[m][n], 0, 0, 0);
            __builtin_amdgcn_s_setprio(0);
        }
    };

    // prologue: stage tiles 0,1 (20 loads); wait tile 0 (10 remain in flight)
    stage(0, 0);
    stage(BUFSZ, BK);
    asm volatile("s_waitcnt vmcnt(10)" ::: "memory");
    __builtin_amdgcn_s_barrier();

    int buf = 0;
    for (int g = 0; g < NT; ++g) {
        compute(buf);                       // tile g (landed, all waves)
        if (g == NT - 1) break;
        __builtin_amdgcn_s_barrier();       // all reads of tile g done
        if (g + 2 < NT) {
            stage(buf, (g + 2) * BK);       // overwrite tile g's buffer
            asm volatile("s_waitcnt vmcnt(10)" ::: "memory");  // tile g+1 landed
        } else {
            asm volatile("s_waitcnt vmcnt(0)" ::: "memory");
        }
        __builtin_amdgcn_s_barrier();       // landing visible to all waves
        buf ^= BUFSZ;
    }

    // ---- epilogue: C/D layout col = lane&15, row = (lane>>4)*4 + v
    const int orow = (lane >> 4) * 4;
    float bv[4];
#pragma unroll
    for (int n = 0; n < 4; ++n) bv[n] = bias[bcol + n * 16 + lr];
#pragma unroll
    for (int m = 0; m < 4; ++m) {
#pragma unroll
        for (int v = 0; v < 4; ++v) {
            const long grow = brow + w * 64 + m * 16 + orow + v;
            float* cp = C + grow * NDIM + bcol + lr;
#pragma unroll
            for (int n = 0; n < 4; ++n)
                cp[n * 16] = acc[m][n][v] + bv[n];
        }
    }
}

extern "C" void kernel_launch(void* const* d_in, const int* in_sizes, int n_in,
                              void* d_out, int out_size, void* d_ws, size_t ws_size,
                              hipStream_t stream) {
    const float* x     = (const float*)d_in[0];
    const float* g0    = (const float*)d_in[1];
    const float* g1    = (const float*)d_in[2];
    const float* alpha = (const float*)d_in[3];
    const float* pds   = (const float*)d_in[4];
    const float* bias  = (const float*)d_in[5];
    const int*   iperm = (const int*)d_in[6];
    const int*   oinv  = (const int*)d_in[7];
    float* out = (float*)d_out;

    ushort* W3 = (ushort*)d_ws;                         // 4096*4096 bf16 = 32MB
    ushort* Xb = (ushort*)d_ws + (size_t)NDIM * KDIM;   // 2048*4096 bf16 = 16MB

    hipLaunchKernelGGL(k_prep, dim3(8192), dim3(256), 0, stream,
                       x, Xb, g0, g1, alpha, pds, iperm, oinv, W3);
    hipLaunchKernelGGL(k_gemm, dim3((M_TOK / BM) * (NDIM / BN)), dim3(256), 0, stream,
                       Xb, W3, bias, out);
}